// Round 3
// baseline (852.208 us; speedup 1.0000x reference)
//
#include <hip/hip_runtime.h>
#include <hip/hip_bf16.h>
#include <math.h>

// Problem constants (fixed by setup_inputs)
#define BATCH 16
#define PGRID 1024              // 32*32 groups per batch image
#define NGRP  (BATCH*PGRID)     // 16384 groups
#define NELEM (NGRP*4)          // 65536 group-elements (rows of the big GEMM)
#define CDIM  256
#define HID   512

// Workspace layout (float offsets). Total floats = 26,165,248 (~105 MB).
#define OFF_N     ((size_t)0)                       // 65536 x 256 normalized (fp32)
#define OFF_GM    ((size_t)16777216)                // 16384 x 256 group mean
#define OFF_VAR   ((size_t)20971520)                // 65536 per-element variance
#define OFF_DRIVE ((size_t)21037056)                // 65536 drive accumulators
#define OFF_RPRE  ((size_t)21102592)                // 65536 resistance pre-softplus
#define OFF_WN    ((size_t)21168128)                // 16384 x 256 weighted-normalized
#define OFF_US    ((size_t)25362432)                // 16384 update_strength
#define OFF_W1TH  ((size_t)25378816)                // 1024x768 bf16-hi (shorts), [col][k]
#define OFF_W1TL  ((size_t)25772032)                // 1024x768 bf16-lo (shorts), [col][k]

// ---------------- bf16 split helpers ----------------
__device__ __forceinline__ unsigned short f2bf(float x) {
  unsigned u = __float_as_uint(x);
  unsigned r = u + 0x7FFFu + ((u >> 16) & 1u);     // RNE
  return (unsigned short)(r >> 16);
}
__device__ __forceinline__ float bf2f(unsigned short h) {
  return __uint_as_float(((unsigned)h) << 16);
}

// ---------------- reductions ----------------
__device__ __forceinline__ void wave_reduce4(float v[4]) {
#pragma unroll
  for (int off = 1; off < 64; off <<= 1) {
#pragma unroll
    for (int i = 0; i < 4; ++i) v[i] += __shfl_xor(v[i], off, 64);
  }
}

__device__ __forceinline__ void block_reduce4(float v[4], float* sh /*16 floats*/) {
  wave_reduce4(v);
  const int lane = threadIdx.x & 63, wid = threadIdx.x >> 6;
  __syncthreads();
  if (lane == 0) {
#pragma unroll
    for (int i = 0; i < 4; ++i) sh[wid * 4 + i] = v[i];
  }
  __syncthreads();
#pragma unroll
  for (int i = 0; i < 4; ++i) v[i] = sh[i] + sh[4 + i] + sh[8 + i] + sh[12 + i];
}

// ---------------- kernel 1: LN + group mean + variance ----------------
// 1 block per group, 256 threads (one per channel).
__global__ __launch_bounds__(256) void prep_kernel(
    const float* __restrict__ states,
    const float* __restrict__ ln_c_g, const float* __restrict__ ln_c_b,
    float* __restrict__ nbuf, float* __restrict__ gmbuf, float* __restrict__ varb,
    float* __restrict__ drive, float* __restrict__ rpre)
{
  __shared__ float sh[16];
  const int g = blockIdx.x;            // 0..16383
  const int b = g >> 10;
  const int p = g & 1023;
  const int py = p >> 5, px = p & 31;
  const int c = threadIdx.x;

  float x[4];
#pragma unroll
  for (int s = 0; s < 4; ++s) {
    const int h = py * 2 + (s >> 1);
    const int w = px * 2 + (s & 1);
    x[s] = states[((size_t)(b * 4096 + h * 64 + w)) * CDIM + c];
  }

  float sum[4] = {x[0], x[1], x[2], x[3]};
  block_reduce4(sum, sh);
  float d[4];
#pragma unroll
  for (int s = 0; s < 4; ++s) d[s] = x[s] - sum[s] * (1.f / 256.f);

  float sq[4] = {d[0]*d[0], d[1]*d[1], d[2]*d[2], d[3]*d[3]};
  block_reduce4(sq, sh);

  const float gg = ln_c_g[c], bb = ln_c_b[c];
  float nn[4];
#pragma unroll
  for (int s = 0; s < 4; ++s)
    nn[s] = d[s] * rsqrtf(sq[s] * (1.f / 256.f) + 1e-5f) * gg + bb;

  const float gmc = 0.25f * (nn[0] + nn[1] + nn[2] + nn[3]);
  float e4[4];
#pragma unroll
  for (int s = 0; s < 4; ++s) { const float t = nn[s] - gmc; e4[s] = t * t; }
  block_reduce4(e4, sh);

  const size_t nb = (size_t)g * 4 * CDIM;
#pragma unroll
  for (int s = 0; s < 4; ++s) nbuf[nb + s * CDIM + c] = nn[s];
  gmbuf[(size_t)g * CDIM + c] = gmc;
  if (c < 4) {
    varb[g * 4 + c] = e4[c] * (1.f / 256.f);
    drive[g * 4 + c] = 0.f;
    rpre[g * 4 + c] = 0.f;
  }
}

// ---------------- kernel 1b: transpose+split W1 -> bf16 hi/lo, [col][k] ----------------
// col 0..511 -> dW1 cols, col 512..1023 -> rW1 cols. k = 0..767.
__global__ __launch_bounds__(256) void prew1_kernel(
    const float* __restrict__ dW1, const float* __restrict__ rW1,
    short* __restrict__ w1th, short* __restrict__ w1tl)
{
  const int col = blockIdx.x;                 // 0..1023
  const float* W1 = (col < 512) ? dW1 : rW1;
  const int cl = (col < 512) ? col : col - 512;
  for (int k = threadIdx.x; k < 768; k += 256) {
    const float x = W1[(size_t)k * HID + cl];
    const unsigned short h = f2bf(x);
    const unsigned short l = f2bf(x - bf2f(h));
    w1th[(size_t)col * 768 + k] = (short)h;
    w1tl[(size_t)col * 768 + k] = (short)l;
  }
}

// ---------------- kernel 2: MFMA split-bf16 fused MLP GEMM ----------------
// C(65536 x 1024) = joint(65536 x 768) @ [dW1 | rW1](768 x 1024), where the
// joint row is synthesized on the fly: k<256 -> n, k<512 -> gm, else n*gm.
// fp32 accuracy via bf16x3: Ah*Bh + Ah*Bl + Al*Bh (RNE hi/lo splits).
// Epilogue: +b1, exact GELU, dot with W2 column, lane-reduce, atomicAdd
// into drive/rpre scalars (one per GEMM row).
// Tile 128x128, BK=32, 4 waves; per wave 4x4 fragments of 16x16x32.
typedef __attribute__((ext_vector_type(8))) short  frag_ab;
typedef __attribute__((ext_vector_type(4))) float  frag_cd;

#define LDS_STRIDE 40   // shorts per row (32 data + 8 pad) -> 80B row stride

__global__ __launch_bounds__(256) void mlp_gemm_mfma(
    const float* __restrict__ nbuf, const float* __restrict__ gmbuf,
    const short* __restrict__ w1th, const short* __restrict__ w1tl,
    const float* __restrict__ db1, const float* __restrict__ rb1,
    const float* __restrict__ dW2, const float* __restrict__ rW2,
    float* __restrict__ drive, float* __restrict__ rpre)
{
  __shared__ __align__(16) short Ah[128 * LDS_STRIDE];
  __shared__ __align__(16) short Al[128 * LDS_STRIDE];
  __shared__ __align__(16) short Bh[128 * LDS_STRIDE];
  __shared__ __align__(16) short Bl[128 * LDS_STRIDE];

  const int tid  = threadIdx.x;
  const int lane = tid & 63;
  const int w    = tid >> 6;        // 4 waves
  const int wm   = w >> 1;          // 0..1 : 64-row half of M-tile
  const int wn   = w & 1;           // 0..1 : 64-col half of N-tile
  const int m_base = blockIdx.x * 128;
  const int n_base = blockIdx.y * 128;

  // A staging: thread -> (row ar, 16 k-elems at ac)
  const int ar = tid >> 1;
  const int ac = (tid & 1) * 16;
  const int e  = m_base + ar;
  const float* nrow = nbuf + (size_t)e * CDIM;
  const float* grow = gmbuf + (size_t)(e >> 2) * CDIM;

  // B staging: thread -> (col bcol, 16 k-elems at bk); source pre-split [col][k]
  const int bcol = tid >> 1;
  const int bk   = (tid & 1) * 16;
  const short* bsrc_h = w1th + (size_t)(n_base + bcol) * 768 + bk;
  const short* bsrc_l = w1tl + (size_t)(n_base + bcol) * 768 + bk;

  frag_cd acc[4][4];
#pragma unroll
  for (int i = 0; i < 4; ++i)
#pragma unroll
    for (int j = 0; j < 4; ++j)
#pragma unroll
      for (int q = 0; q < 4; ++q) acc[i][j][q] = 0.f;

  float va[16];
  float4 vbh0, vbh1, vbl0, vbl1;

#define LOADA(K0) {                                                         \
    const int kb = (K0) & 255;                                              \
    if ((K0) < 256) {                                                       \
      _Pragma("unroll")                                                     \
      for (int q = 0; q < 4; ++q) {                                         \
        const float4 t = *(const float4*)(nrow + kb + ac + q * 4);          \
        va[q*4+0] = t.x; va[q*4+1] = t.y; va[q*4+2] = t.z; va[q*4+3] = t.w; \
      }                                                                     \
    } else if ((K0) < 512) {                                                \
      _Pragma("unroll")                                                     \
      for (int q = 0; q < 4; ++q) {                                         \
        const float4 t = *(const float4*)(grow + kb + ac + q * 4);          \
        va[q*4+0] = t.x; va[q*4+1] = t.y; va[q*4+2] = t.z; va[q*4+3] = t.w; \
      }                                                                     \
    } else {                                                                \
      _Pragma("unroll")                                                     \
      for (int q = 0; q < 4; ++q) {                                         \
        const float4 t = *(const float4*)(nrow + kb + ac + q * 4);          \
        const float4 u = *(const float4*)(grow + kb + ac + q * 4);          \
        va[q*4+0] = t.x*u.x; va[q*4+1] = t.y*u.y;                           \
        va[q*4+2] = t.z*u.z; va[q*4+3] = t.w*u.w;                           \
      }                                                                     \
    }                                                                       \
  }

#define LOADB(K0) {                                                         \
    const float4* ph = (const float4*)(bsrc_h + (K0));                      \
    vbh0 = ph[0]; vbh1 = ph[1];                                             \
    const float4* pl = (const float4*)(bsrc_l + (K0));                      \
    vbl0 = pl[0]; vbl1 = pl[1];                                             \
  }

  LOADA(0); LOADB(0);

  for (int kk = 0; kk < 24; ++kk) {
    __syncthreads();                 // previous iter's fragment reads done
    // convert A to bf16 hi/lo and write LDS
    frag_ab ph0, ph1, pl0, pl1;
#pragma unroll
    for (int i = 0; i < 8; ++i) {
      const unsigned short h = f2bf(va[i]);
      const unsigned short l = f2bf(va[i] - bf2f(h));
      ph0[i] = (short)h; pl0[i] = (short)l;
    }
#pragma unroll
    for (int i = 0; i < 8; ++i) {
      const unsigned short h = f2bf(va[8 + i]);
      const unsigned short l = f2bf(va[8 + i] - bf2f(h));
      ph1[i] = (short)h; pl1[i] = (short)l;
    }
    *(frag_ab*)&Ah[ar * LDS_STRIDE + ac]     = ph0;
    *(frag_ab*)&Ah[ar * LDS_STRIDE + ac + 8] = ph1;
    *(frag_ab*)&Al[ar * LDS_STRIDE + ac]     = pl0;
    *(frag_ab*)&Al[ar * LDS_STRIDE + ac + 8] = pl1;
    *(float4*)&Bh[bcol * LDS_STRIDE + bk]     = vbh0;
    *(float4*)&Bh[bcol * LDS_STRIDE + bk + 8] = vbh1;
    *(float4*)&Bl[bcol * LDS_STRIDE + bk]     = vbl0;
    *(float4*)&Bl[bcol * LDS_STRIDE + bk + 8] = vbl1;
    __syncthreads();

    if (kk < 23) { const int k0 = (kk + 1) * 32; LOADA(k0); LOADB(k0); }

    // fragment reads + MFMA.
    // A-frag (16x32): lane holds row=lane&15, k = 8*(lane>>4) + [0..7]
    // B-frag (32x16): lane holds col=lane&15, same k blocking (B stored [col][k])
    const int kq = 8 * (lane >> 4);
    frag_ab bhf[4], blf[4];
#pragma unroll
    for (int nf = 0; nf < 4; ++nf) {
      const int cb = (wn * 64 + nf * 16 + (lane & 15)) * LDS_STRIDE + kq;
      bhf[nf] = *(frag_ab*)&Bh[cb];
      blf[nf] = *(frag_ab*)&Bl[cb];
    }
#pragma unroll
    for (int mf = 0; mf < 4; ++mf) {
      const int rb = (wm * 64 + mf * 16 + (lane & 15)) * LDS_STRIDE + kq;
      const frag_ab ahf = *(frag_ab*)&Ah[rb];
      const frag_ab alf = *(frag_ab*)&Al[rb];
#pragma unroll
      for (int nf = 0; nf < 4; ++nf) {
        acc[mf][nf] = __builtin_amdgcn_mfma_f32_16x16x32_bf16(ahf, bhf[nf], acc[mf][nf], 0, 0, 0);
        acc[mf][nf] = __builtin_amdgcn_mfma_f32_16x16x32_bf16(ahf, blf[nf], acc[mf][nf], 0, 0, 0);
        acc[mf][nf] = __builtin_amdgcn_mfma_f32_16x16x32_bf16(alf, bhf[nf], acc[mf][nf], 0, 0, 0);
      }
    }
  }

  // Epilogue. C/D layout (m89-verified): col = lane&15, row = 4*(lane>>4)+q.
  const bool is_d = (n_base < 512);
  const float* b1v = is_d ? db1 : rb1;
  const float* W2v = is_d ? dW2 : rW2;
  float* tgt = is_d ? drive : rpre;
  const int joff = n_base - (is_d ? 0 : 512) + wn * 64;

  float part[4][4];
#pragma unroll
  for (int i = 0; i < 4; ++i)
#pragma unroll
    for (int q = 0; q < 4; ++q) part[i][q] = 0.f;

#pragma unroll
  for (int nf = 0; nf < 4; ++nf) {
    const int j = joff + nf * 16 + (lane & 15);
    const float bb = b1v[j];
    const float ww = W2v[j];
#pragma unroll
    for (int mf = 0; mf < 4; ++mf)
#pragma unroll
      for (int q = 0; q < 4; ++q) {
        const float xv = acc[mf][nf][q] + bb;
        const float ge = 0.5f * xv * (1.f + erff(xv * 0.70710678118654752f));
        part[mf][q] = fmaf(ge, ww, part[mf][q]);
      }
  }
  // reduce over the 16 lanes holding different cols (same rows)
#pragma unroll
  for (int off = 1; off < 16; off <<= 1)
#pragma unroll
    for (int mf = 0; mf < 4; ++mf)
#pragma unroll
      for (int q = 0; q < 4; ++q)
        part[mf][q] += __shfl_xor(part[mf][q], off, 64);

  if ((lane & 15) == 0) {
    const int rq = lane >> 4;                 // 0..3 -> row quad within 16
#pragma unroll
    for (int mf = 0; mf < 4; ++mf)
#pragma unroll
      for (int q = 0; q < 4; ++q)
        atomicAdd(&tgt[m_base + wm * 64 + mf * 16 + rq * 4 + q], part[mf][q]);
  }
}

// ---------------- kernel 3: energy -> softmax -> weighted normalized ----------------
__global__ __launch_bounds__(256) void weights_kernel(
    const float* __restrict__ nbuf, const float* __restrict__ drive,
    const float* __restrict__ rpre, const float* __restrict__ varb,
    const float* __restrict__ db2, const float* __restrict__ rb2,
    const float* __restrict__ e_bias,
    float* __restrict__ wn, float* __restrict__ usb)
{
  const int g = blockIdx.x;
  const int c = threadIdx.x;
  const float eb = e_bias[0];
  const float b2d = db2[0], b2r = rb2[0];

  float w[4];
  float mx = 0.f;                       // null logit (0) participates in max
#pragma unroll
  for (int s = 0; s < 4; ++s) {
    const float dr = drive[g * 4 + s] + b2d;
    const float rp = rpre[g * 4 + s] + b2r;
    const float va = varb[g * 4 + s];
    const float sp = fmaxf(rp, 0.f) + log1pf(expf(-fabsf(rp)));  // softplus
    float en = dr / (sp + va + 1e-6f) + eb;
    en = fminf(3.f, fmaxf(-3.f, en));
    w[s] = en;
    mx = fmaxf(mx, en);
  }
  const float nullw = expf(-mx);
  float Z = nullw;
#pragma unroll
  for (int s = 0; s < 4; ++s) { w[s] = expf(w[s] - mx); Z += w[s]; }
  const float inv = 1.f / Z;

  float a = 0.f;
  const size_t nb = (size_t)g * 4 * CDIM;
#pragma unroll
  for (int s = 0; s < 4; ++s) a = fmaf(w[s] * inv, nbuf[nb + s * CDIM + c], a);
  wn[(size_t)g * CDIM + c] = a;
  if (c == 0) usb[g] = 1.f - nullw * inv;
}

// ---------------- kernel 4: candidate GEMM + blend + output LN ----------------
__global__ __launch_bounds__(256) void final_kernel(
    const float* __restrict__ wn, const float* __restrict__ usb,
    const float* __restrict__ vW, const float* __restrict__ vb,
    const float* __restrict__ seed,
    const float* __restrict__ ln_o_g, const float* __restrict__ ln_o_b,
    float* __restrict__ out)
{
  __shared__ float lwn[16][256];
  const int t = threadIdx.x;
  const int g0 = blockIdx.x * 16;
#pragma unroll
  for (int gi = 0; gi < 16; ++gi)
    lwn[gi][t] = wn[(size_t)(g0 + gi) * CDIM + t];
  __syncthreads();

  const int cq = (t & 63) * 4;          // 4 channels per lane
  const int gq = (t >> 6) * 4;          // 4 groups per wave (uniform in wave)

  float acc[4][4];
#pragma unroll
  for (int gi = 0; gi < 4; ++gi)
#pragma unroll
    for (int j = 0; j < 4; ++j) acc[gi][j] = 0.f;

  for (int k = 0; k < 256; ++k) {
    const float4 w4 = *(const float4*)(vW + (size_t)k * CDIM + cq);
#pragma unroll
    for (int gi = 0; gi < 4; ++gi) {
      const float a = lwn[gq + gi][k];  // wave-uniform broadcast read
      acc[gi][0] = fmaf(a, w4.x, acc[gi][0]);
      acc[gi][1] = fmaf(a, w4.y, acc[gi][1]);
      acc[gi][2] = fmaf(a, w4.z, acc[gi][2]);
      acc[gi][3] = fmaf(a, w4.w, acc[gi][3]);
    }
  }

  const float4 sd  = *(const float4*)(seed + cq);
  const float4 og  = *(const float4*)(ln_o_g + cq);
  const float4 ob  = *(const float4*)(ln_o_b + cq);
  const float4 vb4 = *(const float4*)(vb + cq);

#pragma unroll
  for (int gi = 0; gi < 4; ++gi) {
    const float us = usb[g0 + gq + gi];
    float nv[4];
    nv[0] = sd.x + us * (acc[gi][0] + us * vb4.x - sd.x);
    nv[1] = sd.y + us * (acc[gi][1] + us * vb4.y - sd.y);
    nv[2] = sd.z + us * (acc[gi][2] + us * vb4.z - sd.z);
    nv[3] = sd.w + us * (acc[gi][3] + us * vb4.w - sd.w);

    float s = nv[0] + nv[1] + nv[2] + nv[3];
#pragma unroll
    for (int off = 1; off < 64; off <<= 1) s += __shfl_xor(s, off, 64);
    const float m = s * (1.f / 256.f);

    const float d0 = nv[0] - m, d1 = nv[1] - m, d2 = nv[2] - m, d3 = nv[3] - m;
    float q = d0 * d0 + d1 * d1 + d2 * d2 + d3 * d3;
#pragma unroll
    for (int off = 1; off < 64; off <<= 1) q += __shfl_xor(q, off, 64);
    const float rstd = rsqrtf(q * (1.f / 256.f) + 1e-5f);

    float4 o;
    o.x = d0 * rstd * og.x + ob.x;
    o.y = d1 * rstd * og.y + ob.y;
    o.z = d2 * rstd * og.z + ob.z;
    o.w = d3 * rstd * og.w + ob.w;
    *(float4*)(out + (size_t)(g0 + gq + gi) * CDIM + cq) = o;
  }
}

// ---------------- launch ----------------
extern "C" void kernel_launch(void* const* d_in, const int* in_sizes, int n_in,
                              void* d_out, int out_size, void* d_ws, size_t ws_size,
                              hipStream_t stream)
{
  const float* states = (const float*)d_in[0];
  const float* ln_c_g = (const float*)d_in[1];
  const float* ln_c_b = (const float*)d_in[2];
  const float* seed   = (const float*)d_in[3];
  const float* dW1    = (const float*)d_in[4];
  const float* db1    = (const float*)d_in[5];
  const float* dW2    = (const float*)d_in[6];
  const float* db2    = (const float*)d_in[7];
  const float* rW1    = (const float*)d_in[8];
  const float* rb1    = (const float*)d_in[9];
  const float* rW2    = (const float*)d_in[10];
  const float* rb2    = (const float*)d_in[11];
  const float* vW     = (const float*)d_in[12];
  const float* vb     = (const float*)d_in[13];
  const float* e_bias = (const float*)d_in[14];
  const float* ln_o_g = (const float*)d_in[15];
  const float* ln_o_b = (const float*)d_in[16];
  float* out = (float*)d_out;

  float* ws    = (float*)d_ws;
  float* nbuf  = ws + OFF_N;
  float* gmbuf = ws + OFF_GM;
  float* varb  = ws + OFF_VAR;
  float* drive = ws + OFF_DRIVE;
  float* rpre  = ws + OFF_RPRE;
  float* wnb   = ws + OFF_WN;
  float* usb   = ws + OFF_US;
  short* w1th  = (short*)(ws + OFF_W1TH);
  short* w1tl  = (short*)(ws + OFF_W1TL);

  prep_kernel<<<NGRP, 256, 0, stream>>>(states, ln_c_g, ln_c_b,
                                        nbuf, gmbuf, varb, drive, rpre);

  prew1_kernel<<<1024, 256, 0, stream>>>(dW1, rW1, w1th, w1tl);

  dim3 ggrid(512, 8);
  mlp_gemm_mfma<<<ggrid, 256, 0, stream>>>(nbuf, gmbuf, w1th, w1tl,
                                           db1, rb1, dW2, rW2, drive, rpre);

  weights_kernel<<<NGRP, 256, 0, stream>>>(nbuf, drive, rpre, varb,
                                           db2, rb2, e_bias, wnb, usb);

  final_kernel<<<NGRP / 16, 256, 0, stream>>>(wnb, usb, vW, vb, seed,
                                              ln_o_g, ln_o_b, out);
}

// Round 6
// 842.893 us; speedup vs baseline: 1.0111x; 1.0111x over previous
//
#include <hip/hip_runtime.h>
#include <hip/hip_bf16.h>
#include <math.h>

// Problem constants (fixed by setup_inputs)
#define BATCH 16
#define PGRID 1024              // 32*32 groups per batch image
#define NGRP  (BATCH*PGRID)     // 16384 groups
#define NELEM (NGRP*4)          // 65536 group-elements (rows of the big GEMM)
#define CDIM  256
#define HID   512

// Workspace layout (float-slot offsets). Total = 26,165,248 floats (~105 MB),
// identical footprint to the round-3 run that passed.
#define OFF_NH    ((size_t)0)                       // 65536x256 bf16-hi of normalized
#define OFF_NL    ((size_t)8388608)                 // 65536x256 bf16-lo
#define OFF_GMH   ((size_t)16777216)                // 16384x256 bf16-hi of gm
#define OFF_GML   ((size_t)18874368)                // 16384x256 bf16-lo
#define OFF_VAR   ((size_t)20971520)                // 65536 per-element variance
#define OFF_DRIVE ((size_t)21037056)                // 65536 drive accumulators
#define OFF_RPRE  ((size_t)21102592)                // 65536 resistance pre-softplus
#define OFF_WN    ((size_t)21168128)                // 16384x256 weighted-normalized (fp32)
#define OFF_US    ((size_t)25362432)                // 16384 update_strength
#define OFF_W1TH  ((size_t)25378816)                // 1024x768 bf16-hi (shorts), [col][k]
#define OFF_W1TL  ((size_t)25772032)                // 1024x768 bf16-lo (shorts), [col][k]

// ---------------- bf16 split helpers ----------------
__device__ __forceinline__ unsigned short f2bf(float x) {
  unsigned u = __float_as_uint(x);
  unsigned r = u + 0x7FFFu + ((u >> 16) & 1u);     // RNE
  return (unsigned short)(r >> 16);
}
__device__ __forceinline__ float bf2f(unsigned short h) {
  return __uint_as_float(((unsigned)h) << 16);
}

// ---------------- reductions ----------------
__device__ __forceinline__ void wave_reduce4(float v[4]) {
#pragma unroll
  for (int off = 1; off < 64; off <<= 1) {
#pragma unroll
    for (int i = 0; i < 4; ++i) v[i] += __shfl_xor(v[i], off, 64);
  }
}

__device__ __forceinline__ void block_reduce4(float v[4], float* sh /*16 floats*/) {
  wave_reduce4(v);
  const int lane = threadIdx.x & 63, wid = threadIdx.x >> 6;
  __syncthreads();
  if (lane == 0) {
#pragma unroll
    for (int i = 0; i < 4; ++i) sh[wid * 4 + i] = v[i];
  }
  __syncthreads();
#pragma unroll
  for (int i = 0; i < 4; ++i) v[i] = sh[i] + sh[4 + i] + sh[8 + i] + sh[12 + i];
}

// ---------------- kernel 1: LN + group mean + variance + bf16 pre-split ----------------
__global__ __launch_bounds__(256) void prep_kernel(
    const float* __restrict__ states,
    const float* __restrict__ ln_c_g, const float* __restrict__ ln_c_b,
    short* __restrict__ nh, short* __restrict__ nl,
    short* __restrict__ gmh, short* __restrict__ gml,
    float* __restrict__ varb, float* __restrict__ drive, float* __restrict__ rpre)
{
  __shared__ float sh[16];
  const int g = blockIdx.x;            // 0..16383
  const int b = g >> 10;
  const int p = g & 1023;
  const int py = p >> 5, px = p & 31;
  const int c = threadIdx.x;

  float x[4];
#pragma unroll
  for (int s = 0; s < 4; ++s) {
    const int h = py * 2 + (s >> 1);
    const int w = px * 2 + (s & 1);
    x[s] = states[((size_t)(b * 4096 + h * 64 + w)) * CDIM + c];
  }

  float sum[4] = {x[0], x[1], x[2], x[3]};
  block_reduce4(sum, sh);
  float d[4];
#pragma unroll
  for (int s = 0; s < 4; ++s) d[s] = x[s] - sum[s] * (1.f / 256.f);

  float sq[4] = {d[0]*d[0], d[1]*d[1], d[2]*d[2], d[3]*d[3]};
  block_reduce4(sq, sh);

  const float gg = ln_c_g[c], bb = ln_c_b[c];
  float nn[4];
#pragma unroll
  for (int s = 0; s < 4; ++s)
    nn[s] = d[s] * rsqrtf(sq[s] * (1.f / 256.f) + 1e-5f) * gg + bb;

  const float gmc = 0.25f * (nn[0] + nn[1] + nn[2] + nn[3]);
  float e4[4];
#pragma unroll
  for (int s = 0; s < 4; ++s) { const float t = nn[s] - gmc; e4[s] = t * t; }
  block_reduce4(e4, sh);

  const size_t nb = (size_t)g * 4 * CDIM;
#pragma unroll
  for (int s = 0; s < 4; ++s) {
    const unsigned short h = f2bf(nn[s]);
    const unsigned short l = f2bf(nn[s] - bf2f(h));
    nh[nb + s * CDIM + c] = (short)h;
    nl[nb + s * CDIM + c] = (short)l;
  }
  {
    const unsigned short h = f2bf(gmc);
    const unsigned short l = f2bf(gmc - bf2f(h));
    gmh[(size_t)g * CDIM + c] = (short)h;
    gml[(size_t)g * CDIM + c] = (short)l;
  }
  if (c < 4) {
    varb[g * 4 + c] = e4[c] * (1.f / 256.f);
    drive[g * 4 + c] = 0.f;
    rpre[g * 4 + c] = 0.f;
  }
}

// ---------------- kernel 1b: transpose+split W1 -> bf16 hi/lo, [col][k] ----------------
__global__ __launch_bounds__(256) void prew1_kernel(
    const float* __restrict__ dW1, const float* __restrict__ rW1,
    short* __restrict__ w1th, short* __restrict__ w1tl)
{
  const int col = blockIdx.x;                 // 0..1023
  const float* W1 = (col < 512) ? dW1 : rW1;
  const int cl = (col < 512) ? col : col - 512;
  for (int k = threadIdx.x; k < 768; k += 256) {
    const float x = W1[(size_t)k * HID + cl];
    const unsigned short h = f2bf(x);
    const unsigned short l = f2bf(x - bf2f(h));
    w1th[(size_t)col * 768 + k] = (short)h;
    w1tl[(size_t)col * 768 + k] = (short)l;
  }
}

// ---------------- kernel 2: MFMA split-bf16 fused MLP GEMM ----------------
// C(65536 x 1024) = joint(65536 x 768) @ [dW1 | rW1](768 x 1024);
// joint row synthesized: k<256 -> n, k<512 -> gm, else n*gm.
// fp32 accuracy via bf16x3: Ah*Bh + Ah*Bl + Al*Bh. n and gm arrive PRE-SPLIT
// (regions 0/1 stage with zero conversion ALU); region 2 reconstructs the
// fp32 product from hi+lo and re-splits (8 of 24 iters).
//
// LDS layout [sec][row][8] shorts (sec = k/8): fragment read (row r, sec s)
// = byte s*2048 + r*16 -> start bank 4r%32, uniform over all 32 banks.
//
// Grid 4096 1D, XCD-swizzled: bid%8 = XCD; each XCD walks the 8 n-tiles of
// one m-panel consecutively -> A-panel L2-resident (~160KB << 4MB).
typedef __attribute__((ext_vector_type(8))) short  frag_ab;
typedef __attribute__((ext_vector_type(4))) float  frag_cd;

#define AIDX(sec, row) ((sec) * 1024 + (row) * 8)

__global__ __launch_bounds__(256) void mlp_gemm_mfma(
    const short* __restrict__ nh, const short* __restrict__ nl,
    const short* __restrict__ gmh, const short* __restrict__ gml,
    const short* __restrict__ w1th, const short* __restrict__ w1tl,
    const float* __restrict__ db1, const float* __restrict__ rb1,
    const float* __restrict__ dW2, const float* __restrict__ rW2,
    float* __restrict__ drive, float* __restrict__ rpre)
{
  __shared__ __align__(16) short Ah[4096];   // [4][128][8] shorts, 8 KB each
  __shared__ __align__(16) short Al[4096];
  __shared__ __align__(16) short Bh[4096];
  __shared__ __align__(16) short Bl[4096];

  const int tid  = threadIdx.x;
  const int lane = tid & 63;
  const int w    = tid >> 6;        // 4 waves
  const int wm   = w >> 1;          // 0..1 : 64-row half of M-tile
  const int wn   = w & 1;           // 0..1 : 64-col half of N-tile

  // XCD-aware swizzle (bijective: 4096 % 8 == 0).
  const int bid = blockIdx.x;
  const int xcd = bid & 7;
  const int lb  = bid >> 3;                  // 0..511
  const int mt  = xcd * 64 + (lb >> 3);      // m-tile 0..511
  const int nt  = lb & 7;                    // n-tile 0..7 (fast-varying per XCD)
  const int m_base = mt * 128;
  const int n_base = nt * 128;

  // A staging: thread -> (row ar, 16 k-elems at ac)
  const int ar = tid >> 1;
  const int ac = (tid & 1) * 16;
  const int asec = (tid & 1) * 2;            // LDS sections ac/8, ac/8+1
  const int e  = m_base + ar;
  const short* nhrow = nh + (size_t)e * CDIM;
  const short* nlrow = nl + (size_t)e * CDIM;
  const short* ghrow = gmh + (size_t)(e >> 2) * CDIM;
  const short* glrow = gml + (size_t)(e >> 2) * CDIM;

  // B staging: thread -> (col bcol, 16 k-elems at bk); source pre-split [col][k]
  const int bcol = tid >> 1;
  const int bk   = (tid & 1) * 16;
  const int bsec = (tid & 1) * 2;
  const short* bsrc_h = w1th + (size_t)(n_base + bcol) * 768 + bk;
  const short* bsrc_l = w1tl + (size_t)(n_base + bcol) * 768 + bk;

  frag_cd acc[4][4];
#pragma unroll
  for (int i = 0; i < 4; ++i)
#pragma unroll
    for (int j = 0; j < 4; ++j)
#pragma unroll
      for (int q = 0; q < 4; ++q) acc[i][j][q] = 0.f;

  // staged registers: regions 0/1 use sA directly; region 2 uses va (fp32 products)
  frag_ab sA0, sA1, sA2, sA3;
  float va[16];
  frag_ab sB0, sB1, sB2, sB3;

#define LOADA(K0) {                                                          \
    if ((K0) < 256) {                                                        \
      sA0 = *(const frag_ab*)(nhrow + (K0) + ac);                            \
      sA1 = *(const frag_ab*)(nhrow + (K0) + ac + 8);                        \
      sA2 = *(const frag_ab*)(nlrow + (K0) + ac);                            \
      sA3 = *(const frag_ab*)(nlrow + (K0) + ac + 8);                        \
    } else if ((K0) < 512) {                                                 \
      const int kb_ = (K0) - 256;                                            \
      sA0 = *(const frag_ab*)(ghrow + kb_ + ac);                             \
      sA1 = *(const frag_ab*)(ghrow + kb_ + ac + 8);                         \
      sA2 = *(const frag_ab*)(glrow + kb_ + ac);                             \
      sA3 = *(const frag_ab*)(glrow + kb_ + ac + 8);                         \
    } else {                                                                 \
      const int kb_ = (K0) - 512;                                            \
      const frag_ab h0 = *(const frag_ab*)(nhrow + kb_ + ac);                \
      const frag_ab h1 = *(const frag_ab*)(nhrow + kb_ + ac + 8);            \
      const frag_ab l0 = *(const frag_ab*)(nlrow + kb_ + ac);                \
      const frag_ab l1 = *(const frag_ab*)(nlrow + kb_ + ac + 8);            \
      const frag_ab g0 = *(const frag_ab*)(ghrow + kb_ + ac);                \
      const frag_ab g1 = *(const frag_ab*)(ghrow + kb_ + ac + 8);            \
      const frag_ab m0 = *(const frag_ab*)(glrow + kb_ + ac);                \
      const frag_ab m1 = *(const frag_ab*)(glrow + kb_ + ac + 8);            \
      _Pragma("unroll")                                                      \
      for (int i_ = 0; i_ < 8; ++i_) {                                       \
        const float nf = bf2f((unsigned short)h0[i_]) + bf2f((unsigned short)l0[i_]); \
        const float gf = bf2f((unsigned short)g0[i_]) + bf2f((unsigned short)m0[i_]); \
        va[i_] = nf * gf;                                                    \
      }                                                                      \
      _Pragma("unroll")                                                      \
      for (int i_ = 0; i_ < 8; ++i_) {                                       \
        const float nf = bf2f((unsigned short)h1[i_]) + bf2f((unsigned short)l1[i_]); \
        const float gf = bf2f((unsigned short)g1[i_]) + bf2f((unsigned short)m1[i_]); \
        va[8 + i_] = nf * gf;                                                \
      }                                                                      \
    }                                                                        \
  }

#define LOADB(K0) {                                                          \
    sB0 = *(const frag_ab*)(bsrc_h + (K0));                                  \
    sB1 = *(const frag_ab*)(bsrc_h + (K0) + 8);                              \
    sB2 = *(const frag_ab*)(bsrc_l + (K0));                                  \
    sB3 = *(const frag_ab*)(bsrc_l + (K0) + 8);                              \
  }

  LOADA(0); LOADB(0);

  for (int kk = 0; kk < 24; ++kk) {
    __syncthreads();                 // previous iter's fragment reads done
    if (kk < 16) {                   // regions 0/1: pre-split, direct copy
      *(frag_ab*)&Ah[AIDX(asec,     ar)] = sA0;
      *(frag_ab*)&Ah[AIDX(asec + 1, ar)] = sA1;
      *(frag_ab*)&Al[AIDX(asec,     ar)] = sA2;
      *(frag_ab*)&Al[AIDX(asec + 1, ar)] = sA3;
    } else {                         // region 2: split fp32 products now
      frag_ab ph0, ph1, pl0, pl1;
#pragma unroll
      for (int i = 0; i < 8; ++i) {
        const unsigned short h = f2bf(va[i]);
        ph0[i] = (short)h; pl0[i] = (short)f2bf(va[i] - bf2f(h));
      }
#pragma unroll
      for (int i = 0; i < 8; ++i) {
        const unsigned short h = f2bf(va[8 + i]);
        ph1[i] = (short)h; pl1[i] = (short)f2bf(va[8 + i] - bf2f(h));
      }
      *(frag_ab*)&Ah[AIDX(asec,     ar)] = ph0;
      *(frag_ab*)&Ah[AIDX(asec + 1, ar)] = ph1;
      *(frag_ab*)&Al[AIDX(asec,     ar)] = pl0;
      *(frag_ab*)&Al[AIDX(asec + 1, ar)] = pl1;
    }
    *(frag_ab*)&Bh[AIDX(bsec,     bcol)] = sB0;
    *(frag_ab*)&Bh[AIDX(bsec + 1, bcol)] = sB1;
    *(frag_ab*)&Bl[AIDX(bsec,     bcol)] = sB2;
    *(frag_ab*)&Bl[AIDX(bsec + 1, bcol)] = sB3;
    __syncthreads();

    if (kk < 23) { const int k0 = (kk + 1) * 32; LOADA(k0); LOADB(k0); }

    // fragment reads + MFMA.
    // A-frag (16x32): lane holds row=lane&15, k = 8*(lane>>4) + [0..7]
    // B-frag (32x16): lane holds col=lane&15, same k blocking
    const int sec = lane >> 4;
    frag_ab bhf[4], blf[4];
#pragma unroll
    for (int nf = 0; nf < 4; ++nf) {
      const int cb = AIDX(sec, wn * 64 + nf * 16 + (lane & 15));
      bhf[nf] = *(const frag_ab*)&Bh[cb];
      blf[nf] = *(const frag_ab*)&Bl[cb];
    }
#pragma unroll
    for (int mf = 0; mf < 4; ++mf) {
      const int rb = AIDX(sec, wm * 64 + mf * 16 + (lane & 15));
      const frag_ab ahf = *(const frag_ab*)&Ah[rb];
      const frag_ab alf = *(const frag_ab*)&Al[rb];
#pragma unroll
      for (int nf = 0; nf < 4; ++nf) {
        acc[mf][nf] = __builtin_amdgcn_mfma_f32_16x16x32_bf16(ahf, bhf[nf], acc[mf][nf], 0, 0, 0);
        acc[mf][nf] = __builtin_amdgcn_mfma_f32_16x16x32_bf16(ahf, blf[nf], acc[mf][nf], 0, 0, 0);
        acc[mf][nf] = __builtin_amdgcn_mfma_f32_16x16x32_bf16(alf, bhf[nf], acc[mf][nf], 0, 0, 0);
      }
    }
  }

  // Epilogue. C/D layout (m89-verified): col = lane&15, row = 4*(lane>>4)+q.
  const bool is_d = (n_base < 512);
  const float* b1v = is_d ? db1 : rb1;
  const float* W2v = is_d ? dW2 : rW2;
  float* tgt = is_d ? drive : rpre;
  const int joff = n_base - (is_d ? 0 : 512) + wn * 64;

  float part[4][4];
#pragma unroll
  for (int i = 0; i < 4; ++i)
#pragma unroll
    for (int q = 0; q < 4; ++q) part[i][q] = 0.f;

#pragma unroll
  for (int nf = 0; nf < 4; ++nf) {
    const int j = joff + nf * 16 + (lane & 15);
    const float bb = b1v[j];
    const float ww = W2v[j];
#pragma unroll
    for (int mf = 0; mf < 4; ++mf)
#pragma unroll
      for (int q = 0; q < 4; ++q) {
        const float xv = acc[mf][nf][q] + bb;
        const float ge = 0.5f * xv * (1.f + erff(xv * 0.70710678118654752f));
        part[mf][q] = fmaf(ge, ww, part[mf][q]);
      }
  }
  // reduce over the 16 lanes holding different cols (same rows)
#pragma unroll
  for (int off = 1; off < 16; off <<= 1)
#pragma unroll
    for (int mf = 0; mf < 4; ++mf)
#pragma unroll
      for (int q = 0; q < 4; ++q)
        part[mf][q] += __shfl_xor(part[mf][q], off, 64);

  if ((lane & 15) == 0) {
    const int rq = lane >> 4;                 // 0..3 -> row quad within 16
#pragma unroll
    for (int mf = 0; mf < 4; ++mf)
#pragma unroll
      for (int q = 0; q < 4; ++q)
        atomicAdd(&tgt[m_base + wm * 64 + mf * 16 + rq * 4 + q], part[mf][q]);
  }
}

// ---------------- kernel 3: energy -> softmax -> weighted normalized ----------------
__global__ __launch_bounds__(256) void weights_kernel(
    const short* __restrict__ nh, const short* __restrict__ nl,
    const float* __restrict__ drive, const float* __restrict__ rpre,
    const float* __restrict__ varb,
    const float* __restrict__ db2, const float* __restrict__ rb2,
    const float* __restrict__ e_bias,
    float* __restrict__ wn, float* __restrict__ usb)
{
  const int g = blockIdx.x;
  const int c = threadIdx.x;
  const float eb = e_bias[0];
  const float b2d = db2[0], b2r = rb2[0];

  float w[4];
  float mx = 0.f;                       // null logit (0) participates in max
#pragma unroll
  for (int s = 0; s < 4; ++s) {
    const float dr = drive[g * 4 + s] + b2d;
    const float rp = rpre[g * 4 + s] + b2r;
    const float va = varb[g * 4 + s];
    const float sp = fmaxf(rp, 0.f) + log1pf(expf(-fabsf(rp)));  // softplus
    float en = dr / (sp + va + 1e-6f) + eb;
    en = fminf(3.f, fmaxf(-3.f, en));
    w[s] = en;
    mx = fmaxf(mx, en);
  }
  const float nullw = expf(-mx);
  float Z = nullw;
#pragma unroll
  for (int s = 0; s < 4; ++s) { w[s] = expf(w[s] - mx); Z += w[s]; }
  const float inv = 1.f / Z;

  float a = 0.f;
  const size_t nb = (size_t)g * 4 * CDIM;
#pragma unroll
  for (int s = 0; s < 4; ++s) {
    const size_t ix = nb + s * CDIM + c;
    const float nv = bf2f((unsigned short)nh[ix]) + bf2f((unsigned short)nl[ix]);
    a = fmaf(w[s] * inv, nv, a);
  }
  wn[(size_t)g * CDIM + c] = a;
  if (c == 0) usb[g] = 1.f - nullw * inv;
}

// ---------------- kernel 4: candidate GEMM + blend + output LN ----------------
__global__ __launch_bounds__(256) void final_kernel(
    const float* __restrict__ wn, const float* __restrict__ usb,
    const float* __restrict__ vW, const float* __restrict__ vb,
    const float* __restrict__ seed,
    const float* __restrict__ ln_o_g, const float* __restrict__ ln_o_b,
    float* __restrict__ out)
{
  __shared__ float lwn[16][256];
  const int t = threadIdx.x;
  const int g0 = blockIdx.x * 16;
#pragma unroll
  for (int gi = 0; gi < 16; ++gi)
    lwn[gi][t] = wn[(size_t)(g0 + gi) * CDIM + t];
  __syncthreads();

  const int cq = (t & 63) * 4;          // 4 channels per lane
  const int gq = (t >> 6) * 4;          // 4 groups per wave (uniform in wave)

  float acc[4][4];
#pragma unroll
  for (int gi = 0; gi < 4; ++gi)
#pragma unroll
    for (int j = 0; j < 4; ++j) acc[gi][j] = 0.f;

  for (int k = 0; k < 256; ++k) {
    const float4 w4 = *(const float4*)(vW + (size_t)k * CDIM + cq);
#pragma unroll
    for (int gi = 0; gi < 4; ++gi) {
      const float a = lwn[gq + gi][k];  // wave-uniform broadcast read
      acc[gi][0] = fmaf(a, w4.x, acc[gi][0]);
      acc[gi][1] = fmaf(a, w4.y, acc[gi][1]);
      acc[gi][2] = fmaf(a, w4.z, acc[gi][2]);
      acc[gi][3] = fmaf(a, w4.w, acc[gi][3]);
    }
  }

  const float4 sd  = *(const float4*)(seed + cq);
  const float4 og  = *(const float4*)(ln_o_g + cq);
  const float4 ob  = *(const float4*)(ln_o_b + cq);
  const float4 vb4 = *(const float4*)(vb + cq);

#pragma unroll
  for (int gi = 0; gi < 4; ++gi) {
    const float us = usb[g0 + gq + gi];
    float nv[4];
    nv[0] = sd.x + us * (acc[gi][0] + us * vb4.x - sd.x);
    nv[1] = sd.y + us * (acc[gi][1] + us * vb4.y - sd.y);
    nv[2] = sd.z + us * (acc[gi][2] + us * vb4.z - sd.z);
    nv[3] = sd.w + us * (acc[gi][3] + us * vb4.w - sd.w);

    float s = nv[0] + nv[1] + nv[2] + nv[3];
#pragma unroll
    for (int off = 1; off < 64; off <<= 1) s += __shfl_xor(s, off, 64);
    const float m = s * (1.f / 256.f);

    const float d0 = nv[0] - m, d1 = nv[1] - m, d2 = nv[2] - m, d3 = nv[3] - m;
    float q = d0 * d0 + d1 * d1 + d2 * d2 + d3 * d3;
#pragma unroll
    for (int off = 1; off < 64; off <<= 1) q += __shfl_xor(q, off, 64);
    const float rstd = rsqrtf(q * (1.f / 256.f) + 1e-5f);

    float4 o;
    o.x = d0 * rstd * og.x + ob.x;
    o.y = d1 * rstd * og.y + ob.y;
    o.z = d2 * rstd * og.z + ob.z;
    o.w = d3 * rstd * og.w + ob.w;
    *(float4*)(out + (size_t)(g0 + gq + gi) * CDIM + cq) = o;
  }
}

// ---------------- launch ----------------
extern "C" void kernel_launch(void* const* d_in, const int* in_sizes, int n_in,
                              void* d_out, int out_size, void* d_ws, size_t ws_size,
                              hipStream_t stream)
{
  const float* states = (const float*)d_in[0];
  const float* ln_c_g = (const float*)d_in[1];
  const float* ln_c_b = (const float*)d_in[2];
  const float* seed   = (const float*)d_in[3];
  const float* dW1    = (const float*)d_in[4];
  const float* db1    = (const float*)d_in[5];
  const float* dW2    = (const float*)d_in[6];
  const float* db2    = (const float*)d_in[7];
  const float* rW1    = (const float*)d_in[8];
  const float* rb1    = (const float*)d_in[9];
  const float* rW2    = (const float*)d_in[10];
  const float* rb2    = (const float*)d_in[11];
  const float* vW     = (const float*)d_in[12];
  const float* vb     = (const float*)d_in[13];
  const float* e_bias = (const float*)d_in[14];
  const float* ln_o_g = (const float*)d_in[15];
  const float* ln_o_b = (const float*)d_in[16];
  float* out = (float*)d_out;

  float* ws    = (float*)d_ws;
  short* nhb   = (short*)(ws + OFF_NH);
  short* nlb   = (short*)(ws + OFF_NL);
  short* gmhb  = (short*)(ws + OFF_GMH);
  short* gmlb  = (short*)(ws + OFF_GML);
  float* varb  = ws + OFF_VAR;
  float* drive = ws + OFF_DRIVE;
  float* rpre  = ws + OFF_RPRE;
  float* wnb   = ws + OFF_WN;
  float* usb   = ws + OFF_US;
  short* w1th  = (short*)(ws + OFF_W1TH);
  short* w1tl  = (short*)(ws + OFF_W1TL);

  prep_kernel<<<NGRP, 256, 0, stream>>>(states, ln_c_g, ln_c_b,
                                        nhb, nlb, gmhb, gmlb, varb, drive, rpre);

  prew1_kernel<<<1024, 256, 0, stream>>>(dW1, rW1, w1th, w1tl);

  mlp_gemm_mfma<<<4096, 256, 0, stream>>>(nhb, nlb, gmhb, gmlb, w1th, w1tl,
                                          db1, rb1, dW2, rW2, drive, rpre);

  weights_kernel<<<NGRP, 256, 0, stream>>>(nhb, nlb, drive, rpre, varb,
                                           db2, rb2, e_bias, wnb, usb);

  final_kernel<<<NGRP / 16, 256, 0, stream>>>(wnb, usb, vW, vb, seed,
                                              ln_o_g, ln_o_b, out);
}

// Round 7
// 722.329 us; speedup vs baseline: 1.1798x; 1.1669x over previous
//
#include <hip/hip_runtime.h>
#include <hip/hip_bf16.h>
#include <math.h>

// Problem constants (fixed by setup_inputs)
#define BATCH 16
#define PGRID 1024              // 32*32 groups per batch image
#define NGRP  (BATCH*PGRID)     // 16384 groups
#define NELEM (NGRP*4)          // 65536 group-elements (rows of the big GEMM)
#define CDIM  256
#define HID   512

// Workspace layout (float-slot offsets). ~105 MB, same footprint as passing runs.
#define OFF_NH    ((size_t)0)                       // 65536x256 bf16-hi of normalized
#define OFF_NL    ((size_t)8388608)                 // 65536x256 bf16-lo
#define OFF_GMH   ((size_t)16777216)                // 16384x256 bf16-hi of gm
#define OFF_GML   ((size_t)18874368)                // 16384x256 bf16-lo
#define OFF_VAR   ((size_t)20971520)                // 65536 per-element variance
#define OFF_DRIVE ((size_t)21037056)                // 65536 drive accumulators
#define OFF_RPRE  ((size_t)21102592)                // 65536 resistance pre-softplus
#define OFF_WN    ((size_t)21168128)                // 16384x256 weighted-normalized (fp32)
#define OFF_US    ((size_t)25362432)                // 16384 update_strength
#define OFF_W1TH  ((size_t)25378816)                // 1024x768 bf16-hi (shorts), [col][k]
#define OFF_W1TL  ((size_t)25772032)                // 1024x768 bf16-lo (shorts), [col][k]

// ---------------- bf16 split helpers ----------------
__device__ __forceinline__ unsigned short f2bf(float x) {
  unsigned u = __float_as_uint(x);
  unsigned r = u + 0x7FFFu + ((u >> 16) & 1u);     // RNE
  return (unsigned short)(r >> 16);
}
__device__ __forceinline__ float bf2f(unsigned short h) {
  return __uint_as_float(((unsigned)h) << 16);
}

// ---------------- reductions ----------------
__device__ __forceinline__ void wave_reduce4(float v[4]) {
#pragma unroll
  for (int off = 1; off < 64; off <<= 1) {
#pragma unroll
    for (int i = 0; i < 4; ++i) v[i] += __shfl_xor(v[i], off, 64);
  }
}

__device__ __forceinline__ void block_reduce4(float v[4], float* sh /*16 floats*/) {
  wave_reduce4(v);
  const int lane = threadIdx.x & 63, wid = threadIdx.x >> 6;
  __syncthreads();
  if (lane == 0) {
#pragma unroll
    for (int i = 0; i < 4; ++i) sh[wid * 4 + i] = v[i];
  }
  __syncthreads();
#pragma unroll
  for (int i = 0; i < 4; ++i) v[i] = sh[i] + sh[4 + i] + sh[8 + i] + sh[12 + i];
}

// ---------------- kernel 1: LN + group mean + variance + bf16 pre-split ----------------
__global__ __launch_bounds__(256) void prep_kernel(
    const float* __restrict__ states,
    const float* __restrict__ ln_c_g, const float* __restrict__ ln_c_b,
    short* __restrict__ nh, short* __restrict__ nl,
    short* __restrict__ gmh, short* __restrict__ gml,
    float* __restrict__ varb, float* __restrict__ drive, float* __restrict__ rpre)
{
  __shared__ float sh[16];
  const int g = blockIdx.x;            // 0..16383
  const int b = g >> 10;
  const int p = g & 1023;
  const int py = p >> 5, px = p & 31;
  const int c = threadIdx.x;

  float x[4];
#pragma unroll
  for (int s = 0; s < 4; ++s) {
    const int h = py * 2 + (s >> 1);
    const int w = px * 2 + (s & 1);
    x[s] = states[((size_t)(b * 4096 + h * 64 + w)) * CDIM + c];
  }

  float sum[4] = {x[0], x[1], x[2], x[3]};
  block_reduce4(sum, sh);
  float d[4];
#pragma unroll
  for (int s = 0; s < 4; ++s) d[s] = x[s] - sum[s] * (1.f / 256.f);

  float sq[4] = {d[0]*d[0], d[1]*d[1], d[2]*d[2], d[3]*d[3]};
  block_reduce4(sq, sh);

  const float gg = ln_c_g[c], bb = ln_c_b[c];
  float nn[4];
#pragma unroll
  for (int s = 0; s < 4; ++s)
    nn[s] = d[s] * rsqrtf(sq[s] * (1.f / 256.f) + 1e-5f) * gg + bb;

  const float gmc = 0.25f * (nn[0] + nn[1] + nn[2] + nn[3]);
  float e4[4];
#pragma unroll
  for (int s = 0; s < 4; ++s) { const float t = nn[s] - gmc; e4[s] = t * t; }
  block_reduce4(e4, sh);

  const size_t nb = (size_t)g * 4 * CDIM;
#pragma unroll
  for (int s = 0; s < 4; ++s) {
    const unsigned short h = f2bf(nn[s]);
    const unsigned short l = f2bf(nn[s] - bf2f(h));
    nh[nb + s * CDIM + c] = (short)h;
    nl[nb + s * CDIM + c] = (short)l;
  }
  {
    const unsigned short h = f2bf(gmc);
    const unsigned short l = f2bf(gmc - bf2f(h));
    gmh[(size_t)g * CDIM + c] = (short)h;
    gml[(size_t)g * CDIM + c] = (short)l;
  }
  if (c < 4) {
    varb[g * 4 + c] = e4[c] * (1.f / 256.f);
    drive[g * 4 + c] = 0.f;
    rpre[g * 4 + c] = 0.f;
  }
}

// ---------------- kernel 1b: transpose+split W1 -> bf16 hi/lo, [col][k] ----------------
__global__ __launch_bounds__(256) void prew1_kernel(
    const float* __restrict__ dW1, const float* __restrict__ rW1,
    short* __restrict__ w1th, short* __restrict__ w1tl)
{
  const int col = blockIdx.x;                 // 0..1023
  const float* W1 = (col < 512) ? dW1 : rW1;
  const int cl = (col < 512) ? col : col - 512;
  for (int k = threadIdx.x; k < 768; k += 256) {
    const float x = W1[(size_t)k * HID + cl];
    const unsigned short h = f2bf(x);
    const unsigned short l = f2bf(x - bf2f(h));
    w1th[(size_t)col * 768 + k] = (short)h;
    w1tl[(size_t)col * 768 + k] = (short)l;
  }
}

// ---------------- kernel 2: MFMA split-bf16 fused MLP GEMM (pipelined) ----------------
// C(65536 x 1024) = joint(65536 x 768) @ [dW1 | rW1](768 x 1024);
// joint row synthesized: k<256 -> n, k<512 -> gm, else n*gm (hi/lo pre-split).
// fp32 accuracy via bf16x3: Ah*Bh + Ah*Bl + Al*Bh.
//
// PIPELINE (round-7 change): double-buffered LDS, ONE barrier per K-step:
//   iter kk: { issue global loads for tile kk+1 ; ds_read+48 MFMA on buf[cur] ;
//              ds_write tile kk+1 -> buf[cur^1] ; barrier }
// Staging map: thread = (row = tid&127, k-half = tid>>7); each 16-lane quarter
// writes 256B contiguous -> all 32 banks once (write conflicts eliminated).
// LDS layout per buffer: [sec=k/8][row][8] shorts; fragment read (sec=lane>>4,
// row=..+(lane&15)) -> byte sec*2048 + row*16, uniform bank coverage.
// Grid 4096 1D XCD-swizzled (keeps A-panel L2-resident; FETCH ~105MB measured).
typedef __attribute__((ext_vector_type(8))) short  frag_ab;
typedef __attribute__((ext_vector_type(4))) float  frag_cd;

#define AIDX(sec, row) ((sec) * 1024 + (row) * 8)

__global__ __launch_bounds__(256, 2) void mlp_gemm_mfma(
    const short* __restrict__ nh, const short* __restrict__ nl,
    const short* __restrict__ gmh, const short* __restrict__ gml,
    const short* __restrict__ w1th, const short* __restrict__ w1tl,
    const float* __restrict__ db1, const float* __restrict__ rb1,
    const float* __restrict__ dW2, const float* __restrict__ rW2,
    float* __restrict__ drive, float* __restrict__ rpre)
{
  __shared__ __align__(16) short Ah[8192];   // 2 buffers x [4][128][8] shorts
  __shared__ __align__(16) short Al[8192];
  __shared__ __align__(16) short Bh[8192];
  __shared__ __align__(16) short Bl[8192];

  const int tid  = threadIdx.x;
  const int lane = tid & 63;
  const int w    = tid >> 6;        // 4 waves
  const int wm   = w >> 1;          // 0..1 : 64-row half of M-tile
  const int wn   = w & 1;           // 0..1 : 64-col half of N-tile

  // XCD-aware swizzle (bijective: 4096 % 8 == 0).
  const int bid = blockIdx.x;
  const int xcd = bid & 7;
  const int lb  = bid >> 3;                  // 0..511
  const int mt  = xcd * 64 + (lb >> 3);      // m-tile 0..511
  const int nt  = lb & 7;                    // n-tile 0..7 (fast-varying per XCD)
  const int m_base = mt * 128;
  const int n_base = nt * 128;

  // staging map: row (or B col) = tid&127, k-half = tid>>7
  const int srow = tid & 127;
  const int sp   = tid >> 7;                 // 0/1
  const int sp16 = sp * 16;
  const int sp2  = sp * 2;                   // LDS sections sp2, sp2+1

  const short* nhrow = nh  + (size_t)(m_base + srow) * CDIM;
  const short* nlrow = nl  + (size_t)(m_base + srow) * CDIM;
  const short* ghrow = gmh + (size_t)((m_base + srow) >> 2) * CDIM;
  const short* glrow = gml + (size_t)((m_base + srow) >> 2) * CDIM;
  const short* bsrc_h = w1th + (size_t)(n_base + srow) * 768 + sp16;
  const short* bsrc_l = w1tl + (size_t)(n_base + srow) * 768 + sp16;

  frag_cd acc[4][4];
#pragma unroll
  for (int i = 0; i < 4; ++i)
#pragma unroll
    for (int j = 0; j < 4; ++j)
#pragma unroll
      for (int q = 0; q < 4; ++q) acc[i][j][q] = 0.f;

  // prefetch registers (loads issued early; region-2 math deferred to store)
  frag_ab rA0, rA1, rA2, rA3, rA4, rA5, rA6, rA7;
  frag_ab sB0, sB1, sB2, sB3;

#define LOADA(K0) do {                                                   \
    const int k0_ = (K0);                                                \
    if (k0_ < 256) {                                                     \
      const short* p_ = nhrow + k0_ + sp16;                              \
      const short* q_ = nlrow + k0_ + sp16;                              \
      rA0 = *(const frag_ab*)(p_);  rA1 = *(const frag_ab*)(p_ + 8);     \
      rA2 = *(const frag_ab*)(q_);  rA3 = *(const frag_ab*)(q_ + 8);     \
    } else if (k0_ < 512) {                                              \
      const short* p_ = ghrow + (k0_ - 256) + sp16;                      \
      const short* q_ = glrow + (k0_ - 256) + sp16;                      \
      rA0 = *(const frag_ab*)(p_);  rA1 = *(const frag_ab*)(p_ + 8);     \
      rA2 = *(const frag_ab*)(q_);  rA3 = *(const frag_ab*)(q_ + 8);     \
    } else {                                                             \
      const int kb_ = k0_ - 512;                                         \
      const short* p_ = nhrow + kb_ + sp16;                              \
      const short* q_ = nlrow + kb_ + sp16;                              \
      const short* r_ = ghrow + kb_ + sp16;                              \
      const short* s_ = glrow + kb_ + sp16;                              \
      rA0 = *(const frag_ab*)(p_);  rA1 = *(const frag_ab*)(p_ + 8);     \
      rA2 = *(const frag_ab*)(q_);  rA3 = *(const frag_ab*)(q_ + 8);     \
      rA4 = *(const frag_ab*)(r_);  rA5 = *(const frag_ab*)(r_ + 8);     \
      rA6 = *(const frag_ab*)(s_);  rA7 = *(const frag_ab*)(s_ + 8);     \
    }                                                                    \
  } while (0)

#define LOADB(K0) do {                                                   \
    sB0 = *(const frag_ab*)(bsrc_h + (K0));                              \
    sB1 = *(const frag_ab*)(bsrc_h + (K0) + 8);                          \
    sB2 = *(const frag_ab*)(bsrc_l + (K0));                              \
    sB3 = *(const frag_ab*)(bsrc_l + (K0) + 8);                          \
  } while (0)

#define STOREAB(BUF, RAW) do {                                           \
    const int bo_ = (BUF) * 4096;                                        \
    if (RAW) {                                                           \
      *(frag_ab*)&Ah[bo_ + AIDX(sp2,     srow)] = rA0;                   \
      *(frag_ab*)&Ah[bo_ + AIDX(sp2 + 1, srow)] = rA1;                   \
      *(frag_ab*)&Al[bo_ + AIDX(sp2,     srow)] = rA2;                   \
      *(frag_ab*)&Al[bo_ + AIDX(sp2 + 1, srow)] = rA3;                   \
    } else {                                                             \
      frag_ab ph0, ph1, pl0, pl1;                                        \
      _Pragma("unroll")                                                  \
      for (int j_ = 0; j_ < 8; ++j_) {                                   \
        const float n0 = bf2f((unsigned short)rA0[j_]) + bf2f((unsigned short)rA2[j_]); \
        const float g0 = bf2f((unsigned short)rA4[j_]) + bf2f((unsigned short)rA6[j_]); \
        const float p0 = n0 * g0;                                        \
        const unsigned short h0_ = f2bf(p0);                             \
        ph0[j_] = (short)h0_; pl0[j_] = (short)f2bf(p0 - bf2f(h0_));     \
        const float n1 = bf2f((unsigned short)rA1[j_]) + bf2f((unsigned short)rA3[j_]); \
        const float g1 = bf2f((unsigned short)rA5[j_]) + bf2f((unsigned short)rA7[j_]); \
        const float p1 = n1 * g1;                                        \
        const unsigned short h1_ = f2bf(p1);                             \
        ph1[j_] = (short)h1_; pl1[j_] = (short)f2bf(p1 - bf2f(h1_));     \
      }                                                                  \
      *(frag_ab*)&Ah[bo_ + AIDX(sp2,     srow)] = ph0;                   \
      *(frag_ab*)&Ah[bo_ + AIDX(sp2 + 1, srow)] = ph1;                   \
      *(frag_ab*)&Al[bo_ + AIDX(sp2,     srow)] = pl0;                   \
      *(frag_ab*)&Al[bo_ + AIDX(sp2 + 1, srow)] = pl1;                   \
    }                                                                    \
    *(frag_ab*)&Bh[bo_ + AIDX(sp2,     srow)] = sB0;                     \
    *(frag_ab*)&Bh[bo_ + AIDX(sp2 + 1, srow)] = sB1;                     \
    *(frag_ab*)&Bl[bo_ + AIDX(sp2,     srow)] = sB2;                     \
    *(frag_ab*)&Bl[bo_ + AIDX(sp2 + 1, srow)] = sB3;                     \
  } while (0)

  // prologue: stage tile 0 into buffer 0
  LOADA(0); LOADB(0);
  STOREAB(0, true);
  __syncthreads();
  int cur = 0;

  const int l15 = lane & 15;
  const int sec = lane >> 4;

  for (int kk = 0; kk < 24; ++kk) {
    const bool havenext = (kk < 23);
    if (havenext) { const int k0 = (kk + 1) * 32; LOADA(k0); LOADB(k0); }

    // fragment reads + MFMA on buf[cur].
    // A-frag (16x32): lane holds row=lane&15, k = 8*(lane>>4)+[0..7]
    // B-frag (32x16): lane holds col=lane&15, same k blocking
    const int bo = cur * 4096;
    frag_ab bhf[4], blf[4];
#pragma unroll
    for (int nf = 0; nf < 4; ++nf) {
      const int cb = bo + AIDX(sec, wn * 64 + nf * 16 + l15);
      bhf[nf] = *(const frag_ab*)&Bh[cb];
      blf[nf] = *(const frag_ab*)&Bl[cb];
    }
#pragma unroll
    for (int mf = 0; mf < 4; ++mf) {
      const int rb = bo + AIDX(sec, wm * 64 + mf * 16 + l15);
      const frag_ab ahf = *(const frag_ab*)&Ah[rb];
      const frag_ab alf = *(const frag_ab*)&Al[rb];
#pragma unroll
      for (int nf = 0; nf < 4; ++nf) {
        acc[mf][nf] = __builtin_amdgcn_mfma_f32_16x16x32_bf16(ahf, bhf[nf], acc[mf][nf], 0, 0, 0);
        acc[mf][nf] = __builtin_amdgcn_mfma_f32_16x16x32_bf16(ahf, blf[nf], acc[mf][nf], 0, 0, 0);
        acc[mf][nf] = __builtin_amdgcn_mfma_f32_16x16x32_bf16(alf, bhf[nf], acc[mf][nf], 0, 0, 0);
      }
    }

    if (havenext) {
      STOREAB(cur ^ 1, (kk + 1) < 16);   // tiles 0-15 raw, 16-23 = n*gm product
      __syncthreads();
      cur ^= 1;
    }
  }

  // Epilogue. C/D layout (m89-verified): col = lane&15, row = 4*(lane>>4)+q.
  const bool is_d = (n_base < 512);
  const float* b1v = is_d ? db1 : rb1;
  const float* W2v = is_d ? dW2 : rW2;
  float* tgt = is_d ? drive : rpre;
  const int joff = n_base - (is_d ? 0 : 512) + wn * 64;

  float part[4][4];
#pragma unroll
  for (int i = 0; i < 4; ++i)
#pragma unroll
    for (int q = 0; q < 4; ++q) part[i][q] = 0.f;

#pragma unroll
  for (int nf = 0; nf < 4; ++nf) {
    const int j = joff + nf * 16 + l15;
    const float bb = b1v[j];
    const float ww = W2v[j];
#pragma unroll
    for (int mf = 0; mf < 4; ++mf)
#pragma unroll
      for (int q = 0; q < 4; ++q) {
        const float xv = acc[mf][nf][q] + bb;
        const float ge = 0.5f * xv * (1.f + erff(xv * 0.70710678118654752f));
        part[mf][q] = fmaf(ge, ww, part[mf][q]);
      }
  }
  // reduce over the 16 lanes holding different cols (same rows)
#pragma unroll
  for (int off = 1; off < 16; off <<= 1)
#pragma unroll
    for (int mf = 0; mf < 4; ++mf)
#pragma unroll
      for (int q = 0; q < 4; ++q)
        part[mf][q] += __shfl_xor(part[mf][q], off, 64);

  if (l15 == 0) {
    const int rq = lane >> 4;                 // 0..3 -> row quad within 16
#pragma unroll
    for (int mf = 0; mf < 4; ++mf)
#pragma unroll
      for (int q = 0; q < 4; ++q)
        atomicAdd(&tgt[m_base + wm * 64 + mf * 16 + rq * 4 + q], part[mf][q]);
  }
}

// ---------------- kernel 3: energy -> softmax -> weighted normalized ----------------
__global__ __launch_bounds__(256) void weights_kernel(
    const short* __restrict__ nh, const short* __restrict__ nl,
    const float* __restrict__ drive, const float* __restrict__ rpre,
    const float* __restrict__ varb,
    const float* __restrict__ db2, const float* __restrict__ rb2,
    const float* __restrict__ e_bias,
    float* __restrict__ wn, float* __restrict__ usb)
{
  const int g = blockIdx.x;
  const int c = threadIdx.x;
  const float eb = e_bias[0];
  const float b2d = db2[0], b2r = rb2[0];

  float w[4];
  float mx = 0.f;                       // null logit (0) participates in max
#pragma unroll
  for (int s = 0; s < 4; ++s) {
    const float dr = drive[g * 4 + s] + b2d;
    const float rp = rpre[g * 4 + s] + b2r;
    const float va = varb[g * 4 + s];
    const float sp = fmaxf(rp, 0.f) + log1pf(expf(-fabsf(rp)));  // softplus
    float en = dr / (sp + va + 1e-6f) + eb;
    en = fminf(3.f, fmaxf(-3.f, en));
    w[s] = en;
    mx = fmaxf(mx, en);
  }
  const float nullw = expf(-mx);
  float Z = nullw;
#pragma unroll
  for (int s = 0; s < 4; ++s) { w[s] = expf(w[s] - mx); Z += w[s]; }
  const float inv = 1.f / Z;

  float a = 0.f;
  const size_t nb = (size_t)g * 4 * CDIM;
#pragma unroll
  for (int s = 0; s < 4; ++s) {
    const size_t ix = nb + s * CDIM + c;
    const float nv = bf2f((unsigned short)nh[ix]) + bf2f((unsigned short)nl[ix]);
    a = fmaf(w[s] * inv, nv, a);
  }
  wn[(size_t)g * CDIM + c] = a;
  if (c == 0) usb[g] = 1.f - nullw * inv;
}

// ---------------- kernel 4: candidate GEMM + blend + output LN ----------------
__global__ __launch_bounds__(256) void final_kernel(
    const float* __restrict__ wn, const float* __restrict__ usb,
    const float* __restrict__ vW, const float* __restrict__ vb,
    const float* __restrict__ seed,
    const float* __restrict__ ln_o_g, const float* __restrict__ ln_o_b,
    float* __restrict__ out)
{
  __shared__ float lwn[16][256];
  const int t = threadIdx.x;
  const int g0 = blockIdx.x * 16;
#pragma unroll
  for (int gi = 0; gi < 16; ++gi)
    lwn[gi][t] = wn[(size_t)(g0 + gi) * CDIM + t];
  __syncthreads();

  const int cq = (t & 63) * 4;          // 4 channels per lane
  const int gq = (t >> 6) * 4;          // 4 groups per wave (uniform in wave)

  float acc[4][4];
#pragma unroll
  for (int gi = 0; gi < 4; ++gi)
#pragma unroll
    for (int j = 0; j < 4; ++j) acc[gi][j] = 0.f;

  for (int k = 0; k < 256; ++k) {
    const float4 w4 = *(const float4*)(vW + (size_t)k * CDIM + cq);
#pragma unroll
    for (int gi = 0; gi < 4; ++gi) {
      const float a = lwn[gq + gi][k];  // wave-uniform broadcast read
      acc[gi][0] = fmaf(a, w4.x, acc[gi][0]);
      acc[gi][1] = fmaf(a, w4.y, acc[gi][1]);
      acc[gi][2] = fmaf(a, w4.z, acc[gi][2]);
      acc[gi][3] = fmaf(a, w4.w, acc[gi][3]);
    }
  }

  const float4 sd  = *(const float4*)(seed + cq);
  const float4 og  = *(const float4*)(ln_o_g + cq);
  const float4 ob  = *(const float4*)(ln_o_b + cq);
  const float4 vb4 = *(const float4*)(vb + cq);

#pragma unroll
  for (int gi = 0; gi < 4; ++gi) {
    const float us = usb[g0 + gq + gi];
    float nv[4];
    nv[0] = sd.x + us * (acc[gi][0] + us * vb4.x - sd.x);
    nv[1] = sd.y + us * (acc[gi][1] + us * vb4.y - sd.y);
    nv[2] = sd.z + us * (acc[gi][2] + us * vb4.z - sd.z);
    nv[3] = sd.w + us * (acc[gi][3] + us * vb4.w - sd.w);

    float s = nv[0] + nv[1] + nv[2] + nv[3];
#pragma unroll
    for (int off = 1; off < 64; off <<= 1) s += __shfl_xor(s, off, 64);
    const float m = s * (1.f / 256.f);

    const float d0 = nv[0] - m, d1 = nv[1] - m, d2 = nv[2] - m, d3 = nv[3] - m;
    float q = d0 * d0 + d1 * d1 + d2 * d2 + d3 * d3;
#pragma unroll
    for (int off = 1; off < 64; off <<= 1) q += __shfl_xor(q, off, 64);
    const float rstd = rsqrtf(q * (1.f / 256.f) + 1e-5f);

    float4 o;
    o.x = d0 * rstd * og.x + ob.x;
    o.y = d1 * rstd * og.y + ob.y;
    o.z = d2 * rstd * og.z + ob.z;
    o.w = d3 * rstd * og.w + ob.w;
    *(float4*)(out + (size_t)(g0 + gq + gi) * CDIM + cq) = o;
  }
}

// ---------------- launch ----------------
extern "C" void kernel_launch(void* const* d_in, const int* in_sizes, int n_in,
                              void* d_out, int out_size, void* d_ws, size_t ws_size,
                              hipStream_t stream)
{
  const float* states = (const float*)d_in[0];
  const float* ln_c_g = (const float*)d_in[1];
  const float* ln_c_b = (const float*)d_in[2];
  const float* seed   = (const float*)d_in[3];
  const float* dW1    = (const float*)d_in[4];
  const float* db1    = (const float*)d_in[5];
  const float* dW2    = (const float*)d_in[6];
  const float* db2    = (const float*)d_in[7];
  const float* rW1    = (const float*)d_in[8];
  const float* rb1    = (const float*)d_in[9];
  const float* rW2    = (const float*)d_in[10];
  const float* rb2    = (const float*)d_in[11];
  const float* vW     = (const float*)d_in[12];
  const float* vb     = (const float*)d_in[13];
  const float* e_bias = (const float*)d_in[14];
  const float* ln_o_g = (const float*)d_in[15];
  const float* ln_o_b = (const float*)d_in[16];
  float* out = (float*)d_out;

  float* ws    = (float*)d_ws;
  short* nhb   = (short*)(ws + OFF_NH);
  short* nlb   = (short*)(ws + OFF_NL);
  short* gmhb  = (short*)(ws + OFF_GMH);
  short* gmlb  = (short*)(ws + OFF_GML);
  float* varb  = ws + OFF_VAR;
  float* drive = ws + OFF_DRIVE;
  float* rpre  = ws + OFF_RPRE;
  float* wnb   = ws + OFF_WN;
  float* usb   = ws + OFF_US;
  short* w1th  = (short*)(ws + OFF_W1TH);
  short* w1tl  = (short*)(ws + OFF_W1TL);

  prep_kernel<<<NGRP, 256, 0, stream>>>(states, ln_c_g, ln_c_b,
                                        nhb, nlb, gmhb, gmlb, varb, drive, rpre);

  prew1_kernel<<<1024, 256, 0, stream>>>(dW1, rW1, w1th, w1tl);

  mlp_gemm_mfma<<<4096, 256, 0, stream>>>(nhb, nlb, gmhb, gmlb, w1th, w1tl,
                                          db1, rb1, dW2, rW2, drive, rpre);

  weights_kernel<<<NGRP, 256, 0, stream>>>(nhb, nlb, drive, rpre, varb,
                                           db2, rb2, e_bias, wnb, usb);

  final_kernel<<<NGRP / 16, 256, 0, stream>>>(wnb, usb, vW, vb, seed,
                                              ln_o_g, ln_o_b, out);
}